// Round 4
// baseline (421.598 us; speedup 1.0000x reference)
//
#include <hip/hip_runtime.h>
#include <hip/hip_bf16.h>

// VQ-VAE vector quantizer, MI355X (gfx950).
//   inputs : z (8,256,16,16,16) fp32, codebook (1024,256) fp32
//   output : quant (8,256,16,16,16) ++ idx (8,16,16,16) ++ loss (1), fp32 flat
//
// Round 4: BIT-REPLICATE the np fp32 reference distance computation.
//   D[n,k] = fl32( fl32(Sz[n] + Se[k]) - 2*dot[n,k] )
//   - Sz/Se: numpy pairwise summation order (256 = two 128-blocks, each with
//     8 interleaved accumulators combined ((r0+r1)+(r2+r3))+((r4+r5)+(r6+r7))).
//   - dot: single sequential fp32 FMA chain over d ascending (= BLAS sgemm
//     microkernel accumulation for K=256 within one KC block).
//   - all non-FMA arithmetic via __fmul_rn/__fadd_rn/__fsub_rn so
//     -ffp-contract=fast cannot re-fuse and change rounding.
//   - argmin: strict '<', k ascending == np.argmin first-occurrence (ties on
//     the ulp(256)-quantized grid are common and meaningful).

#define K_CODES 1024
#define DIM 256
#define N_TOK 32768
#define SPATIAL 4096
#define B_SZ 8
#define SPLIT 4
#define KPB (K_CODES / SPLIT)
#define CHUNK 64

// ws layout in floats (~2.2 MB)
#define WS_LOSS 0
#define WS_E2 16            // 1024 floats: Se[k]
#define WS_SZ 2048          // 32768 floats: Sz[n]
#define WS_ET 36864         // 262144 floats: eT[d][k]
#define WS_PAIRS 299008     // float2 per (split, token): 262144 floats

#define O_IDX (B_SZ * DIM * SPATIAL)  // 8388608
#define O_LOSS (O_IDX + N_TOK)        // 8421376

// numpy pairwise over 128 contiguous fp32 values (8-accumulator block form)
__device__ __forceinline__ float np_pairwise128(const float* x) {
  float r[8];
#pragma unroll
  for (int j = 0; j < 8; j++) r[j] = x[j];
  for (int i = 8; i < 128; i += 8) {
#pragma unroll
    for (int j = 0; j < 8; j++) r[j] = __fadd_rn(r[j], x[i + j]);
  }
  return __fadd_rn(__fadd_rn(__fadd_rn(r[0], r[1]), __fadd_rn(r[2], r[3])),
                   __fadd_rn(__fadd_rn(r[4], r[5]), __fadd_rn(r[6], r[7])));
}

// prep: transpose codebook into eT[d][k]; Se[k] with numpy pairwise order.
__global__ __launch_bounds__(256) void prep_kernel(const float* __restrict__ e,
                                                   float* __restrict__ ws) {
  __shared__ float sq[DIM];
  int k = blockIdx.x;
  int d = threadIdx.x;
  float v = e[k * DIM + d];
  ws[WS_ET + d * K_CODES + k] = v;
  sq[d] = __fmul_rn(v, v);
  __syncthreads();
  if (d == 0) {
    ws[WS_E2 + k] = __fadd_rn(np_pairwise128(sq), np_pairwise128(sq + 128));
    if (k == 0) ws[WS_LOSS] = 0.f;
  }
}

// zsum: Sz[n] with numpy pairwise order (streaming, 8 accumulators per block).
__global__ __launch_bounds__(256) void zsum_kernel(const float* __restrict__ z,
                                                   float* __restrict__ ws) {
  int n = blockIdx.x * 256 + threadIdx.x;
  int b = n >> 12, s = n & 4095;
  const float* zp = z + (size_t)b * DIM * SPATIAL + s;
  float total = 0.f;
#pragma unroll
  for (int blk = 0; blk < 2; blk++) {
    float r[8];
#pragma unroll
    for (int j = 0; j < 8; j++) {
      float zv = zp[(size_t)(blk * 128 + j) * SPATIAL];
      r[j] = __fmul_rn(zv, zv);
    }
    for (int i = 8; i < 128; i += 8) {
#pragma unroll
      for (int j = 0; j < 8; j++) {
        float zv = zp[(size_t)(blk * 128 + i + j) * SPATIAL];
        r[j] = __fadd_rn(r[j], __fmul_rn(zv, zv));
      }
    }
    float res = __fadd_rn(__fadd_rn(__fadd_rn(r[0], r[1]), __fadd_rn(r[2], r[3])),
                          __fadd_rn(__fadd_rn(r[4], r[5]), __fadd_rn(r[6], r[7])));
    total = (blk == 0) ? res : __fadd_rn(total, res);
  }
  ws[WS_SZ + n] = total;
}

__global__ __launch_bounds__(256) void scores_kernel(const float* __restrict__ z,
                                                     const float* __restrict__ ws,
                                                     float2* __restrict__ pairs) {
  int n = blockIdx.x * 256 + threadIdx.x;  // token id
  int b = n >> 12, s = n & 4095;
  const float* zp = z + (size_t)b * DIM * SPATIAL + s;  // stride SPATIAL per d
  const float* eT = ws + WS_ET;
  const float* E2 = ws + WS_E2;
  float Szn = ws[WS_SZ + n];
  int kbase = blockIdx.y * KPB;

  float minv = 3.4e38f;
  int mini = kbase;
  for (int chunk = 0; chunk < KPB; chunk += CHUNK) {
    int k0 = kbase + chunk;
    float acc[CHUNK];
#pragma unroll
    for (int c = 0; c < CHUNK; c++) acc[c] = 0.f;
    const float* eTk = eT + k0;
    for (int d = 0; d < DIM; d++) {
      float zr = zp[(size_t)d * SPATIAL];    // coalesced across lanes
      const float* er = eTk + d * K_CODES;   // uniform address -> s_load
#pragma unroll
      for (int c = 0; c < CHUNK; c++) acc[c] = fmaf(zr, er[c], acc[c]);
    }
#pragma unroll
    for (int c = 0; c < CHUNK; c++) {
      // np order: (Sz + Se) - 2*dot, each step fp32-rounded, no contraction
      float t1 = __fadd_rn(Szn, E2[k0 + c]);
      float D = __fsub_rn(t1, __fmul_rn(2.0f, acc[c]));
      if (D < minv) { minv = D; mini = k0 + c; }  // strict <: first occurrence
    }
  }
  pairs[blockIdx.y * N_TOK + n] = make_float2(minv, __int_as_float(mini));
}

__global__ __launch_bounds__(256) void output_kernel(const float* __restrict__ z,
                                                     const float* __restrict__ e,
                                                     const float2* __restrict__ pairs,
                                                     float* __restrict__ out,
                                                     float* __restrict__ ws) {
  int n = blockIdx.x * 256 + threadIdx.x;
  int b = n >> 12, s = n & 4095;

  // merge 4 splits ascending: strict < keeps earliest k on quantized ties
  float minv = 3.4e38f;
  int mini = 0;
#pragma unroll
  for (int j = 0; j < SPLIT; j++) {
    float2 p = pairs[j * N_TOK + n];
    if (p.x < minv) { minv = p.x; mini = __float_as_int(p.y); }
  }

  out[O_IDX + n] = (float)mini;

  const float* zp = z + (size_t)b * DIM * SPATIAL + s;
  const float* erow = e + (size_t)mini * DIM;
  float* op = out + (size_t)b * DIM * SPATIAL + s;
  float sumsq = 0.f;
  for (int d = 0; d < DIM; d++) {
    float v = erow[d];
    float zv = zp[(size_t)d * SPATIAL];
    float df = v - zv;
    sumsq = fmaf(df, df, sumsq);
    op[(size_t)d * SPATIAL] = v;  // exact fp32 row copy, coalesced along s
  }
#pragma unroll
  for (int o = 32; o > 0; o >>= 1) sumsq += __shfl_down(sumsq, o, 64);
  __shared__ float red[4];
  if ((threadIdx.x & 63) == 0) red[threadIdx.x >> 6] = sumsq;
  __syncthreads();
  if (threadIdx.x == 0) atomicAdd(ws + WS_LOSS, red[0] + red[1] + red[2] + red[3]);
}

__global__ void loss_kernel(const float* __restrict__ ws, float* __restrict__ out) {
  // vq_loss = q_latent + COMMITMENT*e_latent; identical forward -> 1.25 * mean
  out[O_LOSS] = 1.25f * ws[WS_LOSS] / 8388608.f;
}

extern "C" void kernel_launch(void* const* d_in, const int* in_sizes, int n_in,
                              void* d_out, int out_size, void* d_ws, size_t ws_size,
                              hipStream_t stream) {
  const float* z = (const float*)d_in[0];
  const float* e = (const float*)d_in[1];
  float* ws = (float*)d_ws;
  float* out = (float*)d_out;
  float2* pairs = (float2*)(ws + WS_PAIRS);

  prep_kernel<<<K_CODES, 256, 0, stream>>>(e, ws);
  zsum_kernel<<<N_TOK / 256, 256, 0, stream>>>(z, ws);
  scores_kernel<<<dim3(N_TOK / 256, SPLIT), 256, 0, stream>>>(z, ws, pairs);
  output_kernel<<<N_TOK / 256, 256, 0, stream>>>(z, e, pairs, out, ws);
  loss_kernel<<<1, 1, 0, stream>>>(ws, out);
}

// Round 5
// 409.619 us; speedup vs baseline: 1.0292x; 1.0292x over previous
//
#include <hip/hip_runtime.h>
#include <hip/hip_bf16.h>

// VQ-VAE vector quantizer, MI355X (gfx950).
//   inputs : z (8,256,16,16,16) fp32, codebook (1024,256) fp32
//   output : quant (8,256,16,16,16) ++ idx (8,16,16,16) ++ loss (1), fp32 flat
//
// Round 5: fused block-tile kernel, bit-exact np fp32 distance pipeline
// (verified in round 4): D[n,k] = fl32( fl32(Sz[n]+Se[k]) - 2*dot[n,k] ),
// dot = single ascending-d fp32 FMA chain, Sz/Se in numpy pairwise order,
// argmin strict '<' in ascending k (first occurrence).
//
// Structure: block = 64 tokens. z-tile -> LDS once (64 KB, [d][tok] layout,
// conflict-free). 4 waves x 8 chunks x 32 register accumulators; codebook
// values via wave-uniform scalar loads from transposed eT. Fused epilogue:
// cross-wave argmin merge (ascending k), idx write, quant gather+store, loss.

#define K_CODES 1024
#define DIM 256
#define N_TOK 32768
#define SPATIAL 4096
#define TOK_BLK 64
#define CHUNK 32

// ws layout in floats
#define WS_LOSS 0
#define WS_E2 16            // 1024 floats: Se[k]
#define WS_ET 2048          // 262144 floats: eT[d][k]

#define O_IDX (8 * DIM * SPATIAL)     // 8388608
#define O_LOSS (O_IDX + N_TOK)        // 8421376

// numpy pairwise over 128 contiguous fp32 values (8-accumulator block form)
__device__ __forceinline__ float np_pairwise128(const float* x) {
  float r[8];
#pragma unroll
  for (int j = 0; j < 8; j++) r[j] = x[j];
  for (int i = 8; i < 128; i += 8) {
#pragma unroll
    for (int j = 0; j < 8; j++) r[j] = __fadd_rn(r[j], x[i + j]);
  }
  return __fadd_rn(__fadd_rn(__fadd_rn(r[0], r[1]), __fadd_rn(r[2], r[3])),
                   __fadd_rn(__fadd_rn(r[4], r[5]), __fadd_rn(r[6], r[7])));
}

// prep: transpose codebook into eT[d][k]; Se[k] in numpy pairwise order.
__global__ __launch_bounds__(256) void prep_kernel(const float* __restrict__ e,
                                                   float* __restrict__ ws) {
  __shared__ float sq[DIM];
  int k = blockIdx.x;
  int d = threadIdx.x;
  float v = e[k * DIM + d];
  ws[WS_ET + d * K_CODES + k] = v;
  sq[d] = __fmul_rn(v, v);
  __syncthreads();
  if (d == 0) {
    ws[WS_E2 + k] = __fadd_rn(np_pairwise128(sq), np_pairwise128(sq + 128));
    if (k == 0) ws[WS_LOSS] = 0.f;
  }
}

__global__ __launch_bounds__(256, 2) void main_kernel(const float* __restrict__ z,
                                                      const float* __restrict__ e,
                                                      float* __restrict__ ws,
                                                      float* __restrict__ out) {
  __shared__ float zl[DIM * TOK_BLK];  // 64 KB, layout [d][tok]
  __shared__ float pwv[4 * TOK_BLK];
  __shared__ int pwi[4 * TOK_BLK];
  __shared__ int mini_sh[TOK_BLK];
  __shared__ float red[4];

  int tid = threadIdx.x;
  int w = tid >> 6, lane = tid & 63;
  int n0 = blockIdx.x * TOK_BLK;  // 64 blocks per batch: tile never crosses b
  int b = n0 >> 12, s0 = n0 & 4095;
  const float* zbase = z + ((size_t)b * DIM) * SPATIAL + s0;

  // ---- stage z-tile to LDS (float4, fully coalesced; 2-way bank = free) ----
#pragma unroll
  for (int i = 0; i < 16; i++) {
    int idx4 = i * 256 + tid;        // 4096 float4s = 16384 floats
    int d = idx4 >> 4, q = idx4 & 15;
    float4 v = *(const float4*)(zbase + (size_t)d * SPATIAL + q * 4);
    *(float4*)(zl + d * TOK_BLK + q * 4) = v;
  }
  __syncthreads();

  // ---- Sz for this lane's token, numpy pairwise order (bit-exact) ----
  float Szn;
  {
    float total = 0.f;
#pragma unroll
    for (int blk = 0; blk < 2; blk++) {
      float r[8];
#pragma unroll
      for (int j = 0; j < 8; j++) {
        float v = zl[(blk * 128 + j) * TOK_BLK + lane];
        r[j] = __fmul_rn(v, v);
      }
      for (int i = 8; i < 128; i += 8) {
#pragma unroll
        for (int j = 0; j < 8; j++) {
          float v = zl[(blk * 128 + i + j) * TOK_BLK + lane];
          r[j] = __fadd_rn(r[j], __fmul_rn(v, v));
        }
      }
      float res = __fadd_rn(__fadd_rn(__fadd_rn(r[0], r[1]), __fadd_rn(r[2], r[3])),
                            __fadd_rn(__fadd_rn(r[4], r[5]), __fadd_rn(r[6], r[7])));
      total = (blk == 0) ? res : __fadd_rn(total, res);
    }
    Szn = total;
  }

  // ---- distance scan: wave w covers codes [w*256, w*256+256), ascending ----
  const float* eT = ws + WS_ET;
  const float* Se = ws + WS_E2;
  int wbase = __builtin_amdgcn_readfirstlane(w) * 256;  // force wave-uniform
  float minv = 3.4e38f;
  int mini = wbase;
  for (int c = 0; c < 8; c++) {
    int k0 = wbase + c * CHUNK;
    float acc[CHUNK];
#pragma unroll
    for (int j = 0; j < CHUNK; j++) acc[j] = 0.f;
    const float* ep = eT + k0;
    for (int d = 0; d < DIM; d++) {
      float zr = zl[d * TOK_BLK + lane];     // ds_read_b32, conflict-free
      const float* er = ep + d * K_CODES;    // wave-uniform -> s_load
#pragma unroll
      for (int j = 0; j < CHUNK; j++) acc[j] = fmaf(zr, er[j], acc[j]);
    }
#pragma unroll
    for (int j = 0; j < CHUNK; j++) {
      // np order: (Sz + Se) - 2*dot, each step fp32-rounded, no contraction
      float t1 = __fadd_rn(Szn, Se[k0 + j]);
      float D = __fsub_rn(t1, __fmul_rn(2.0f, acc[j]));
      if (D < minv) { minv = D; mini = k0 + j; }  // strict <: first occurrence
    }
  }
  pwv[w * TOK_BLK + lane] = minv;
  pwi[w * TOK_BLK + lane] = mini;
  __syncthreads();

  // ---- cross-wave merge in ascending-k (= ascending wave) order ----
  if (tid < TOK_BLK) {
    float mv = pwv[lane];
    int mi = pwi[lane];
#pragma unroll
    for (int j = 1; j < 4; j++) {
      float v = pwv[j * TOK_BLK + lane];
      if (v < mv) { mv = v; mi = pwi[j * TOK_BLK + lane]; }
    }
    mini_sh[lane] = mi;
    out[O_IDX + n0 + lane] = (float)mi;  // coalesced
  }
  __syncthreads();

  // ---- quant gather + store + loss ----
  int m = mini_sh[lane];
  const float* erow = e + (size_t)m * DIM;  // per-lane row (L2-resident)
  float* op = out + ((size_t)b * DIM) * SPATIAL + s0;
  float sumsq = 0.f;
  for (int i = 0; i < 64; i++) {
    int d = w * 64 + i;                     // wave-uniform d
    float v = erow[d];                      // 64-lane gather, same column
    float zv = zl[d * TOK_BLK + lane];
    float df = __fsub_rn(v, zv);
    sumsq = fmaf(df, df, sumsq);
    op[(size_t)d * SPATIAL + lane] = v;     // coalesced 64-wide store
  }
#pragma unroll
  for (int o = 32; o > 0; o >>= 1) sumsq += __shfl_down(sumsq, o, 64);
  if (lane == 0) red[w] = sumsq;
  __syncthreads();
  if (tid == 0) atomicAdd(ws + WS_LOSS, red[0] + red[1] + red[2] + red[3]);
}

__global__ void loss_kernel(const float* __restrict__ ws, float* __restrict__ out) {
  // vq_loss = q_latent + COMMITMENT*e_latent; identical forward -> 1.25 * mean
  out[O_LOSS] = 1.25f * ws[WS_LOSS] / 8388608.f;
}

extern "C" void kernel_launch(void* const* d_in, const int* in_sizes, int n_in,
                              void* d_out, int out_size, void* d_ws, size_t ws_size,
                              hipStream_t stream) {
  const float* z = (const float*)d_in[0];
  const float* e = (const float*)d_in[1];
  float* ws = (float*)d_ws;
  float* out = (float*)d_out;

  prep_kernel<<<K_CODES, 256, 0, stream>>>(e, ws);
  main_kernel<<<N_TOK / TOK_BLK, 256, 0, stream>>>(z, e, ws, out);
  loss_kernel<<<1, 1, 0, stream>>>(ws, out);
}

// Round 6
// 206.920 us; speedup vs baseline: 2.0375x; 1.9796x over previous
//
#include <hip/hip_runtime.h>
#include <hip/hip_bf16.h>

// VQ-VAE vector quantizer, MI355X (gfx950).
//   inputs : z (8,256,16,16,16) fp32, codebook (1024,256) fp32
//   output : quant (8,256,16,16,16) ++ idx (8,16,16,16) ++ loss (1), fp32 flat
//
// Round 6: bf16-MFMA candidate filter + exact np-fp32 recheck.
//   Phase C (filter): block = 64 tokens, wave w owns tokens w*16..w*16+15.
//     A-frags (z) in registers; codebook staged 64-codes-at-a-time into LDS in
//     pre-swizzled MFMA B-fragment order (conflict-free base+lane*16 reads).
//     Approx score A(k) = Se[k] - 2*dot_mfma; per-token running min (thr) +
//     candidate append when A(k) < thr + M  (M = 1e-3 covers bf16 rounding +
//     MFMA accumulation-order noise + 2 ulp(256) quantization slack).
//   Phase D (recheck): exact verified pipeline D = fl(fl(Sz+Se)-2*dot),
//     dot = single ascending-d fp32 FMA chain, Sz/Se numpy pairwise order;
//     lex-min (D, k) == np.argmin first occurrence. Overflow(>CAP) -> exact
//     full scan by the whole wave (deterministic).
//   Phase E: idx/quant/loss epilogue (identical to the verified round-5 one).

#define K_CODES 1024
#define DIM 256
#define N_TOK 32768
#define SPATIAL 4096
#define TOK_BLK 64
#define CAP 28
#define MARGIN 1e-3f

typedef __attribute__((ext_vector_type(8))) short short8;
typedef __attribute__((ext_vector_type(4))) float float4v;

// ws layout in floats
#define WS_LOSS 0
#define WS_E2 16      // 1024 floats: Se[k] (np pairwise)
#define WS_EB 2048    // 262144 bf16 = 131072 floats: codebook, B-fragment order

#define O_IDX (8 * DIM * SPATIAL)  // 8388608
#define O_LOSS (O_IDX + N_TOK)     // 8421376

__device__ __forceinline__ float np_pairwise128(const float* x) {
  float r[8];
#pragma unroll
  for (int j = 0; j < 8; j++) r[j] = x[j];
  for (int i = 8; i < 128; i += 8) {
#pragma unroll
    for (int j = 0; j < 8; j++) r[j] = __fadd_rn(r[j], x[i + j]);
  }
  return __fadd_rn(__fadd_rn(__fadd_rn(r[0], r[1]), __fadd_rn(r[2], r[3])),
                   __fadd_rn(__fadd_rn(r[4], r[5]), __fadd_rn(r[6], r[7])));
}

__device__ __forceinline__ short f2bf(float v) {  // RTNE fp32->bf16 bits
  unsigned u = __float_as_uint(v);
  u = (u + 0x7fffu + ((u >> 16) & 1u)) >> 16;
  return (short)u;
}

// prep: Se[k] np-pairwise; codebook -> bf16 in MFMA B-fragment order:
//   element for (code k, dim d): stage=k>>6, ct=(k>>4)&3, nn=k&15,
//   f=d>>5, q=(d>>3)&3, j=d&7 -> off = ((((stage*4+ct)*8+f)*64+(q*16+nn))*8+j)
__global__ __launch_bounds__(256) void prep_kernel(const float* __restrict__ e,
                                                   float* __restrict__ ws) {
  __shared__ float sq[DIM];
  int k = blockIdx.x, d = threadIdx.x;
  float v = e[k * DIM + d];
  int stage = k >> 6, ct = (k >> 4) & 3, nn = k & 15;
  int f = d >> 5, q = (d >> 3) & 3, j = d & 7;
  int off = ((((stage * 4 + ct) * 8 + f) * 64 + (q * 16 + nn)) * 8 + j);
  ((short*)(ws + WS_EB))[off] = f2bf(v);
  sq[d] = __fmul_rn(v, v);
  __syncthreads();
  if (d == 0) {
    ws[WS_E2 + k] = __fadd_rn(np_pairwise128(sq), np_pairwise128(sq + 128));
    if (k == 0) ws[WS_LOSS] = 0.f;
  }
}

__global__ __launch_bounds__(256, 2) void main_kernel(const float* __restrict__ z,
                                                      const float* __restrict__ e,
                                                      float* __restrict__ ws,
                                                      float* __restrict__ out) {
  __shared__ __align__(16) short Bst[64 * 256];  // 32 KB, fragment order
  __shared__ unsigned short cand[TOK_BLK][CAP];
  __shared__ float cands[TOK_BLK][CAP];
  __shared__ float aminv[TOK_BLK];
  __shared__ int cnt[TOK_BLK];
  __shared__ float Szs[TOK_BLK];
  __shared__ int mini_sh[TOK_BLK];
  __shared__ float red[4];

  int tid = threadIdx.x, w = tid >> 6, lane = tid & 63;
  int quad = lane >> 4, nn = lane & 15;
  int n0 = blockIdx.x * TOK_BLK;
  int b = n0 >> 12, s0 = n0 & 4095;
  const float* zb = z + (size_t)b * DIM * SPATIAL + s0;
  const float* Se = ws + WS_E2;
  if (tid < TOK_BLK) cnt[tid] = 0;

  // ---- Sz (exact np pairwise) for this wave's 16 tokens, lanes 0..15 ----
  if (quad == 0) {
    const float* zp = zb + w * 16 + nn;
    float total = 0.f;
#pragma unroll
    for (int blk = 0; blk < 2; blk++) {
      float r[8];
#pragma unroll
      for (int j = 0; j < 8; j++) {
        float v = zp[(size_t)(blk * 128 + j) * SPATIAL];
        r[j] = __fmul_rn(v, v);
      }
      for (int i = 8; i < 128; i += 8) {
#pragma unroll
        for (int j = 0; j < 8; j++) {
          float v = zp[(size_t)(blk * 128 + i + j) * SPATIAL];
          r[j] = __fadd_rn(r[j], __fmul_rn(v, v));
        }
      }
      float res = __fadd_rn(__fadd_rn(__fadd_rn(r[0], r[1]), __fadd_rn(r[2], r[3])),
                            __fadd_rn(__fadd_rn(r[4], r[5]), __fadd_rn(r[6], r[7])));
      total = (blk == 0) ? res : __fadd_rn(total, res);
    }
    Szs[w * 16 + nn] = total;
  }

  // ---- A fragments (z -> bf16) in registers: token m = w*16+nn,
  //      frag f holds k-dim d = f*32 + quad*8 + j ----
  int tokA = w * 16 + nn;
  short8 A[8];
#pragma unroll
  for (int f = 0; f < 8; f++) {
    short8 a;
#pragma unroll
    for (int j = 0; j < 8; j++) {
      int d = f * 32 + quad * 8 + j;
      a[j] = f2bf(zb[(size_t)d * SPATIAL + tokA]);
    }
    A[f] = a;
  }

  // ---- Phase C: MFMA filter over 16 stages of 64 codes ----
  const uint4* eBg = (const uint4*)(ws + WS_EB);  // 2048 uint4 per stage
  float thr[4] = {3.4e38f, 3.4e38f, 3.4e38f, 3.4e38f};
  for (int stage = 0; stage < 16; stage++) {
    __syncthreads();  // prior-stage LDS reads done (also orders cnt=0)
#pragma unroll
    for (int i = 0; i < 8; i++)  // 32 KB: coalesced global, canonical LDS
      ((uint4*)Bst)[i * 256 + tid] = eBg[(size_t)stage * 2048 + i * 256 + tid];
    __syncthreads();  // data ready

    for (int ct = 0; ct < 4; ct++) {
      int kbase = stage * 64 + ct * 16;
      float4v C = {0.f, 0.f, 0.f, 0.f};
      const short8* Bp = (const short8*)Bst + ct * 8 * 64;
#pragma unroll
      for (int f = 0; f < 8; f++) {
        short8 Bf = Bp[f * 64 + lane];  // ds_read_b128, conflict-free
        C = __builtin_amdgcn_mfma_f32_16x16x32_bf16(A[f], Bf, C, 0, 0, 0);
      }
      float SeK = Se[kbase + nn];  // col = code = nn
      float sv[4];
      bool pr[4];
#pragma unroll
      for (int r = 0; r < 4; r++) {  // row = token = quad*4 + r
        float s = fmaf(-2.f, C[r], SeK);
        float m = s;  // rowmin across the 16 lanes of this row
        m = fminf(m, __shfl_xor(m, 1, 16));
        m = fminf(m, __shfl_xor(m, 2, 16));
        m = fminf(m, __shfl_xor(m, 4, 16));
        m = fminf(m, __shfl_xor(m, 8, 16));
        thr[r] = fminf(thr[r], m);
        sv[r] = s;
        pr[r] = s < thr[r] + MARGIN;
      }
      if (__ballot(pr[0] | pr[1] | pr[2] | pr[3])) {  // rare path
#pragma unroll
        for (int r = 0; r < 4; r++) {
          unsigned long long bl = __ballot(pr[r]);
          unsigned grp = (unsigned)((bl >> (quad * 16)) & 0xffffULL);
          if (grp) {
            int tb = w * 16 + quad * 4 + r;
            int base = cnt[tb];
            if (pr[r]) {
              int pos = base + __popc(grp & ((1u << nn) - 1u));
              if (pos < CAP) {
                cand[tb][pos] = (unsigned short)(kbase + nn);
                cands[tb][pos] = sv[r];
              }
            }
            if (nn == 0) cnt[tb] = base + __popc(grp);
          }
        }
      }
    }
  }
  // publish per-token final approx min (for recheck skip filter)
#pragma unroll
  for (int r = 0; r < 4; r++)
    if (nn == 0) aminv[w * 16 + quad * 4 + r] = thr[r];

  // ---- Phase D: exact recheck (wave-private tokens; no barrier needed) ----
  int tb = w * 16 + nn;  // lane handles token nn, candidate slots quad::4
  int cc = cnt[tb];
  int cl = cc < CAP ? cc : CAP;
  float bestD = 3.4e38f;
  int bestk = 0x7fffffff;
  {
    const float* zp = zb + tb;
    float amin = aminv[tb], Szn = Szs[tb];
    for (int c = quad; c < cl; c += 4) {
      if (cands[tb][c] >= amin + MARGIN) continue;  // pruned
      int k = cand[tb][c];
      const float* er = e + (size_t)k * DIM;
      float acc = 0.f;
      for (int d = 0; d < DIM; d++) acc = fmaf(zp[(size_t)d * SPATIAL], er[d], acc);
      float D = __fsub_rn(__fadd_rn(Szn, Se[k]), __fmul_rn(2.f, acc));
      if (D < bestD || (D == bestD && k < bestk)) { bestD = D; bestk = k; }
    }
  }
#pragma unroll
  for (int off = 32; off >= 16; off >>= 1) {  // merge the 4 quads per token
    float oD = __shfl_down(bestD, off);
    int ok = __shfl_down(bestk, off);
    if (oD < bestD || (oD == bestD && ok < bestk)) { bestD = oD; bestk = ok; }
  }
  if (lane < 16 && cnt[w * 16 + lane] <= CAP) {
    mini_sh[w * 16 + lane] = bestk;
    out[O_IDX + n0 + w * 16 + lane] = (float)bestk;
  }
  // overflow tokens: exact full scan by the whole wave (deterministic)
  for (int t = 0; t < 16; t++) {
    int tb2 = w * 16 + t;
    if (cnt[tb2] > CAP) {
      const float* zq = zb + tb2;
      float Szn = Szs[tb2];
      float bD = 3.4e38f;
      int bk = 0x7fffffff;
      for (int k = lane; k < K_CODES; k += 64) {
        const float* er = e + (size_t)k * DIM;
        float acc = 0.f;
        for (int d = 0; d < DIM; d++) acc = fmaf(zq[(size_t)d * SPATIAL], er[d], acc);
        float D = __fsub_rn(__fadd_rn(Szn, Se[k]), __fmul_rn(2.f, acc));
        if (D < bD || (D == bD && k < bk)) { bD = D; bk = k; }
      }
#pragma unroll
      for (int m = 1; m < 64; m <<= 1) {
        float oD = __shfl_xor(bD, m);
        int ok = __shfl_xor(bk, m);
        if (oD < bD || (oD == bD && ok < bk)) { bD = oD; bk = ok; }
      }
      if (lane == 0) {
        mini_sh[tb2] = bk;
        out[O_IDX + n0 + tb2] = (float)bk;
      }
    }
  }
  __syncthreads();

  // ---- Phase E: quant gather + store + loss (verified round-5 structure) ----
  int mten = mini_sh[lane];  // lane = token
  const float* erow = e + (size_t)mten * DIM;
  float* op = out + (size_t)b * DIM * SPATIAL + s0;
  float sumsq = 0.f;
  for (int i = 0; i < 64; i++) {
    int d = w * 64 + i;  // wave-uniform d
    float v = erow[d];
    float zv = zb[(size_t)d * SPATIAL + lane];
    float df = __fsub_rn(v, zv);
    sumsq = fmaf(df, df, sumsq);
    op[(size_t)d * SPATIAL + lane] = v;  // coalesced 64-wide store
  }
#pragma unroll
  for (int o = 32; o > 0; o >>= 1) sumsq += __shfl_down(sumsq, o, 64);
  if (lane == 0) red[w] = sumsq;
  __syncthreads();
  if (tid == 0) atomicAdd(ws + WS_LOSS, red[0] + red[1] + red[2] + red[3]);
}

__global__ void loss_kernel(const float* __restrict__ ws, float* __restrict__ out) {
  out[O_LOSS] = 1.25f * ws[WS_LOSS] / 8388608.f;
}

extern "C" void kernel_launch(void* const* d_in, const int* in_sizes, int n_in,
                              void* d_out, int out_size, void* d_ws, size_t ws_size,
                              hipStream_t stream) {
  const float* z = (const float*)d_in[0];
  const float* e = (const float*)d_in[1];
  float* ws = (float*)d_ws;
  float* out = (float*)d_out;

  prep_kernel<<<K_CODES, 256, 0, stream>>>(e, ws);
  main_kernel<<<N_TOK / TOK_BLK, 256, 0, stream>>>(z, e, ws, out);
  loss_kernel<<<1, 1, 0, stream>>>(ws, out);
}